// Round 6
// baseline (277.949 us; speedup 1.0000x reference)
//
#include <hip/hip_runtime.h>

// MultiEnhanceGroupFusionHead:
//   4x grouped 7x7 xcorr (SAME pad) -> *0.001 -> concat(32ch) -> 1x1 conv(128) -> global avg pool
// Mean commutes with conv: only 49 clipped-rectangle sums R per (n,ch) map are needed:
//   R[oy,ox] = Total - (boundary row strips) - (boundary col strips) + (corner overlaps)
// out[n,o] = b[o] + (0.001/4096) * sum_c W[o,c] * sum_m sum_taps z_l[n,32*oc+m,tap] * R[n,32*oc+m,tap]
//   with c = l*8 + oc.
//
// Round 6: single-kernel via last-block-per-sample fusion (release/acquire through
// device-scope atomics, rocPRIM decoupled-lookback idiom). 64-counter memsetAsync
// per call. Falls back to the two-kernel path if ws is too small.

__device__ __forceinline__ void fuse_sample(
    const float* __restrict__ P, const float* __restrict__ W,
    const float* __restrict__ B, float* __restrict__ out, int n, int t)
{
    __shared__ float ps[256][4];   // P for this sample: [ch][level]
    __shared__ float S[32];
    const float4 pv = reinterpret_cast<const float4*>(P)[(size_t)n * 256 + t];
    ps[t][0] = pv.x; ps[t][1] = pv.y; ps[t][2] = pv.z; ps[t][3] = pv.w;
    __syncthreads();
    if (t < 32) {
        const int l = t >> 3, oc = t & 7;   // concat channel c = l*8 + oc
        float s = 0.f;
        #pragma unroll
        for (int m = 0; m < 32; ++m) s += ps[oc * 32 + m][l];
        S[t] = s;
    }
    __syncthreads();
    if (t < 128) {
        const float scale = 0.001f / 4096.0f;   // OUT_SCALE / (H*W)
        float acc = 0.f;
        const float* wr = W + t * 32;
        #pragma unroll
        for (int c = 0; c < 32; ++c) acc += wr[c] * S[c];
        out[n * 128 + t] = fmaf(acc, scale, B[t]);
    }
}

template <int FUSED>
__global__ __launch_bounds__(256) void xcorr_mean_wave(
    const float* __restrict__ x,
    const float* __restrict__ z0, const float* __restrict__ z1,
    const float* __restrict__ z2, const float* __restrict__ z3,
    const float* __restrict__ W, const float* __restrict__ B,
    float* __restrict__ P,       // [16384][4]
    int* __restrict__ cnt,       // [64] zeroed per call (FUSED only)
    float* __restrict__ out)     // [64][128] (FUSED only)
{
    const int wave = threadIdx.x >> 6;
    const int l    = threadIdx.x & 63;
    const int map  = blockIdx.x * 4 + wave;          // n*256 + ch
    const int g = l >> 4, cg = l & 15;

    // Lane l, round k: float4 index k*64 + l  ->  row = k*4 + (l>>4), cols 4*(l&15)..+3
    const float4* __restrict__ xv = reinterpret_cast<const float4*>(x) + (size_t)map * 1024;

    float4 v[16];
    #pragma unroll
    for (int k = 0; k < 16; ++k) v[k] = xv[k * 64 + l];

    // Prefetch this lane's z taps behind the x loads (hides tail HBM latency).
    const float* zl = (g == 0) ? z0 : (g == 1) ? z1 : (g == 2) ? z2 : z3;
    const float* zp = zl + (size_t)map * 49;
    float zq[4];
    #pragma unroll
    for (int j = 0; j < 4; ++j) {
        const int t = cg + 16 * j;
        zq[j] = (t < 49) ? zp[t] : 0.f;
    }

    // per-lane column partials (lane's 4 cols are fixed across rounds)
    float cs0 = 0.f, cs1 = 0.f, cs2 = 0.f, cs3 = 0.f;
    #pragma unroll
    for (int k = 0; k < 16; ++k) { cs0 += v[k].x; cs1 += v[k].y; cs2 += v[k].z; cs3 += v[k].w; }

    // boundary-row partials: round 0 holds rows 0..3, round 15 holds rows 60..63
    float rp_lo = v[0].x + v[0].y + v[0].z + v[0].w;
    float rp_hi = v[15].x + v[15].y + v[15].z + v[15].w;

    // full column sums: reduce across the 4 row-subgroups (xor 16,32)
    #pragma unroll
    for (int off = 16; off < 64; off <<= 1) {
        cs0 += __shfl_xor(cs0, off);
        cs1 += __shfl_xor(cs1, off);
        cs2 += __shfl_xor(cs2, off);
        cs3 += __shfl_xor(cs3, off);
    }
    // total: sum this lane's 4 full col-sums, reduce across 16 col-groups
    float tot = cs0 + cs1 + cs2 + cs3;
    #pragma unroll
    for (int off = 1; off < 16; off <<= 1) tot += __shfl_xor(tot, off);

    // boundary row sums: reduce within each 16-lane group (xor 1..8)
    #pragma unroll
    for (int off = 1; off < 16; off <<= 1) {
        rp_lo += __shfl_xor(rp_lo, off);
        rp_hi += __shfl_xor(rp_hi, off);
    }

    // Per-wave LDS scratch: [0..5] rowsum(0,1,2,61,62,63), [8..13] colsum(0,1,2,61,62,63),
    // [16+6a+b] corner[a][b], [60] total, [64..112] Rtab
    __shared__ float sm[4][128];
    float* s = sm[wave];

    if (cg == 0) {
        if (g < 3)  s[g] = rp_lo;                    // rows 0,1,2
        if (g >= 1) s[2 + g] = rp_hi;                // rows 61,62,63
        if (g == 0) { s[8] = cs0; s[9] = cs1; s[10] = cs2; }   // cols 0,1,2
    }
    if (cg == 15 && g == 0) { s[11] = cs1; s[12] = cs2; s[13] = cs3; }  // cols 61,62,63

    {   // corners: raw x at rows{0,1,2,61,62,63} x cols{0,1,2,61,62,63}
        const float4 a = v[0], b = v[15];
        if (cg == 0) {
            if (g < 3)  { s[16 + 6*g + 0] = a.x; s[16 + 6*g + 1] = a.y; s[16 + 6*g + 2] = a.z; }
            if (g >= 1) { const int r = 2 + g;
                          s[16 + 6*r + 0] = b.x; s[16 + 6*r + 1] = b.y; s[16 + 6*r + 2] = b.z; }
        }
        if (cg == 15) {
            if (g < 3)  { s[16 + 6*g + 3] = a.y; s[16 + 6*g + 4] = a.z; s[16 + 6*g + 5] = a.w; }
            if (g >= 1) { const int r = 2 + g;
                          s[16 + 6*r + 3] = b.y; s[16 + 6*r + 4] = b.z; s[16 + 6*r + 5] = b.w; }
        }
    }
    if (l == 0) s[60] = tot;
    __syncthreads();

    // 49 clipped-rectangle sums
    if (l < 49) {
        const int dy = l / 7, dx = l % 7;
        const int oy = dy - 3, ox = dx - 3;
        const int ty = oy > 0 ? oy : 0, by = oy < 0 ? -oy : 0;
        const int lx = ox > 0 ? ox : 0, rx = ox < 0 ? -ox : 0;
        float R = s[60];
        for (int i = 0; i < ty; ++i) R -= s[i];          // top rows 0..ty-1
        for (int i = 0; i < by; ++i) R -= s[5 - i];      // bottom rows 63,62,..
        for (int i = 0; i < lx; ++i) R -= s[8 + i];      // left cols
        for (int i = 0; i < rx; ++i) R -= s[13 - i];     // right cols
        for (int a = 0; a < ty; ++a) {
            for (int b = 0; b < lx; ++b) R += s[16 + 6*a + b];
            for (int b = 0; b < rx; ++b) R += s[16 + 6*a + (5 - b)];
        }
        for (int a = 0; a < by; ++a) {
            for (int b = 0; b < lx; ++b) R += s[16 + 6*(5 - a) + b];
            for (int b = 0; b < rx; ++b) R += s[16 + 6*(5 - a) + (5 - b)];
        }
        s[64 + l] = R;
    }
    __syncthreads();

    // 4 parallel 16-lane groups: group g dots Rtab with (prefetched) z_g taps
    float acc = 0.f;
    #pragma unroll
    for (int j = 0; j < 4; ++j) {
        const int t = cg + 16 * j;
        acc += zq[j] * (t < 49 ? s[64 + t] : 0.f);
    }
    #pragma unroll
    for (int off = 1; off < 16; off <<= 1) acc += __shfl_xor(acc, off);
    if (cg == 0) P[map * 4 + g] = acc;

    if (FUSED) {
        // ---- last-block-per-sample fusion (release/acquire) ----
        const int n = blockIdx.x >> 6;           // 64 blocks per sample
        __shared__ int lastFlag;
        __syncthreads();                          // drains vmcnt: P stores complete
        if (threadIdx.x == 0) {
            __threadfence();                      // release: writeback local L2
            lastFlag = (atomicAdd(&cnt[n], 1) == 63) ? 1 : 0;
        }
        __syncthreads();
        if (!lastFlag) return;
        __threadfence();                          // acquire: invalidate before reading P
        fuse_sample(P, W, B, out, n, threadIdx.x);
    }
}

__global__ __launch_bounds__(256) void fuse_kernel(
    const float* __restrict__ P, const float* __restrict__ W,
    const float* __restrict__ B, float* __restrict__ out)
{
    fuse_sample(P, W, B, out, blockIdx.x, threadIdx.x);
}

extern "C" void kernel_launch(void* const* d_in, const int* in_sizes, int n_in,
                              void* d_out, int out_size, void* d_ws, size_t ws_size,
                              hipStream_t stream) {
    const float* z0 = (const float*)d_in[0];
    const float* z1 = (const float*)d_in[1];
    const float* z2 = (const float*)d_in[2];
    const float* z3 = (const float*)d_in[3];
    const float* x  = (const float*)d_in[4];
    const float* Wm = (const float*)d_in[5];
    const float* Bm = (const float*)d_in[6];
    float* out = (float*)d_out;

    // ws layout: [0,256) counters (64 ints), [256, 256+262144) P
    const size_t need = 256 + 16384 * 4 * sizeof(float);
    if (ws_size >= need) {
        int* cnt = (int*)d_ws;
        float* P = (float*)((char*)d_ws + 256);
        hipMemsetAsync(cnt, 0, 64 * sizeof(int), stream);
        hipLaunchKernelGGL((xcorr_mean_wave<1>), dim3(4096), dim3(256), 0, stream,
                           x, z0, z1, z2, z3, Wm, Bm, P, cnt, out);
    } else {
        float* P = (float*)d_ws;
        hipLaunchKernelGGL((xcorr_mean_wave<0>), dim3(4096), dim3(256), 0, stream,
                           x, z0, z1, z2, z3, Wm, Bm, P, (int*)nullptr, out);
        hipLaunchKernelGGL(fuse_kernel, dim3(64), dim3(256), 0, stream, P, Wm, Bm, out);
    }
}

// Round 7
// 51.484 us; speedup vs baseline: 5.3987x; 5.3987x over previous
//
#include <hip/hip_runtime.h>

// MultiEnhanceGroupFusionHead:
//   4x grouped 7x7 xcorr (SAME pad) -> *0.001 -> concat(32ch) -> 1x1 conv(128) -> global avg pool
// Mean commutes with conv: only 49 clipped-rectangle sums R per (n,ch) map are needed:
//   R[oy,ox] = Total - (boundary row strips) - (boundary col strips) + (corner overlaps)
// out[n,o] = b[o] + (0.001/4096) * sum_c W[o,c] * sum_m sum_taps z_l[n,32*oc+m,tap] * R[n,32*oc+m,tap]
//   with c = l*8 + oc.
//
// Round 7: revert round-6 fusion (per-block __threadfence = L2 writeback x4096 blocks
// -> 278us catastrophe). Back to two-kernel round-5 structure. New: all LDS is
// wave-private, so replace the two block barriers with wave-local lgkmcnt waits.

#define WAVE_LDS_SYNC() asm volatile("s_waitcnt lgkmcnt(0)" ::: "memory")

__global__ __launch_bounds__(256) void xcorr_mean_wave(
    const float* __restrict__ x,
    const float* __restrict__ z0, const float* __restrict__ z1,
    const float* __restrict__ z2, const float* __restrict__ z3,
    float* __restrict__ P)  // [16384][4]
{
    const int wave = threadIdx.x >> 6;
    const int l    = threadIdx.x & 63;
    const int map  = blockIdx.x * 4 + wave;          // n*256 + ch
    const int g = l >> 4, cg = l & 15;

    // Lane l, round k: float4 index k*64 + l  ->  row = k*4 + (l>>4), cols 4*(l&15)..+3
    const float4* __restrict__ xv = reinterpret_cast<const float4*>(x) + (size_t)map * 1024;

    float4 v[16];
    #pragma unroll
    for (int k = 0; k < 16; ++k) v[k] = xv[k * 64 + l];

    // Prefetch this lane's z taps behind the x loads (hides tail HBM latency).
    const float* zl = (g == 0) ? z0 : (g == 1) ? z1 : (g == 2) ? z2 : z3;
    const float* zp = zl + (size_t)map * 49;
    float zq[4];
    #pragma unroll
    for (int j = 0; j < 4; ++j) {
        const int t = cg + 16 * j;
        zq[j] = (t < 49) ? zp[t] : 0.f;
    }

    // per-lane column partials (lane's 4 cols are fixed across rounds)
    float cs0 = 0.f, cs1 = 0.f, cs2 = 0.f, cs3 = 0.f;
    #pragma unroll
    for (int k = 0; k < 16; ++k) { cs0 += v[k].x; cs1 += v[k].y; cs2 += v[k].z; cs3 += v[k].w; }

    // boundary-row partials: round 0 holds rows 0..3, round 15 holds rows 60..63
    float rp_lo = v[0].x + v[0].y + v[0].z + v[0].w;
    float rp_hi = v[15].x + v[15].y + v[15].z + v[15].w;

    // full column sums: reduce across the 4 row-subgroups (xor 16,32)
    #pragma unroll
    for (int off = 16; off < 64; off <<= 1) {
        cs0 += __shfl_xor(cs0, off);
        cs1 += __shfl_xor(cs1, off);
        cs2 += __shfl_xor(cs2, off);
        cs3 += __shfl_xor(cs3, off);
    }
    // total: sum this lane's 4 full col-sums, reduce across 16 col-groups
    float tot = cs0 + cs1 + cs2 + cs3;
    #pragma unroll
    for (int off = 1; off < 16; off <<= 1) tot += __shfl_xor(tot, off);

    // boundary row sums: reduce within each 16-lane group (xor 1..8)
    #pragma unroll
    for (int off = 1; off < 16; off <<= 1) {
        rp_lo += __shfl_xor(rp_lo, off);
        rp_hi += __shfl_xor(rp_hi, off);
    }

    // Per-wave LDS scratch (wave-private slice -> no block barrier needed):
    // [0..5] rowsum(0,1,2,61,62,63), [8..13] colsum(0,1,2,61,62,63),
    // [16+6a+b] corner[a][b], [60] total, [64..112] Rtab
    __shared__ float sm[4][128];
    float* s = sm[wave];

    if (cg == 0) {
        if (g < 3)  s[g] = rp_lo;                    // rows 0,1,2
        if (g >= 1) s[2 + g] = rp_hi;                // rows 61,62,63
        if (g == 0) { s[8] = cs0; s[9] = cs1; s[10] = cs2; }   // cols 0,1,2
    }
    if (cg == 15 && g == 0) { s[11] = cs1; s[12] = cs2; s[13] = cs3; }  // cols 61,62,63

    {   // corners: raw x at rows{0,1,2,61,62,63} x cols{0,1,2,61,62,63}
        const float4 a = v[0], b = v[15];
        if (cg == 0) {
            if (g < 3)  { s[16 + 6*g + 0] = a.x; s[16 + 6*g + 1] = a.y; s[16 + 6*g + 2] = a.z; }
            if (g >= 1) { const int r = 2 + g;
                          s[16 + 6*r + 0] = b.x; s[16 + 6*r + 1] = b.y; s[16 + 6*r + 2] = b.z; }
        }
        if (cg == 15) {
            if (g < 3)  { s[16 + 6*g + 3] = a.y; s[16 + 6*g + 4] = a.z; s[16 + 6*g + 5] = a.w; }
            if (g >= 1) { const int r = 2 + g;
                          s[16 + 6*r + 3] = b.y; s[16 + 6*r + 4] = b.z; s[16 + 6*r + 5] = b.w; }
        }
    }
    if (l == 0) s[60] = tot;
    WAVE_LDS_SYNC();   // same-wave producers/consumers: lgkmcnt(0) suffices

    // 49 clipped-rectangle sums
    if (l < 49) {
        const int dy = l / 7, dx = l % 7;
        const int oy = dy - 3, ox = dx - 3;
        const int ty = oy > 0 ? oy : 0, by = oy < 0 ? -oy : 0;
        const int lx = ox > 0 ? ox : 0, rx = ox < 0 ? -ox : 0;
        float R = s[60];
        for (int i = 0; i < ty; ++i) R -= s[i];          // top rows 0..ty-1
        for (int i = 0; i < by; ++i) R -= s[5 - i];      // bottom rows 63,62,..
        for (int i = 0; i < lx; ++i) R -= s[8 + i];      // left cols
        for (int i = 0; i < rx; ++i) R -= s[13 - i];     // right cols
        for (int a = 0; a < ty; ++a) {
            for (int b = 0; b < lx; ++b) R += s[16 + 6*a + b];
            for (int b = 0; b < rx; ++b) R += s[16 + 6*a + (5 - b)];
        }
        for (int a = 0; a < by; ++a) {
            for (int b = 0; b < lx; ++b) R += s[16 + 6*(5 - a) + b];
            for (int b = 0; b < rx; ++b) R += s[16 + 6*(5 - a) + (5 - b)];
        }
        s[64 + l] = R;
    }
    WAVE_LDS_SYNC();

    // 4 parallel 16-lane groups: group g dots Rtab with (prefetched) z_g taps
    float acc = 0.f;
    #pragma unroll
    for (int j = 0; j < 4; ++j) {
        const int t = cg + 16 * j;
        acc += zq[j] * (t < 49 ? s[64 + t] : 0.f);
    }
    #pragma unroll
    for (int off = 1; off < 16; off <<= 1) acc += __shfl_xor(acc, off);
    if (cg == 0) P[map * 4 + g] = acc;
}

__global__ __launch_bounds__(256) void fuse_kernel(
    const float* __restrict__ P,   // [64*256][4]
    const float* __restrict__ W,   // [128][32] (merged_w[:,:,0,0])
    const float* __restrict__ B,   // [128]
    float* __restrict__ out)       // [64][128]
{
    const int n = blockIdx.x;
    const int t = threadIdx.x;
    __shared__ float ps[256][4];   // P for this sample: [ch][level]
    __shared__ float S[32];

    // coalesced: thread t reads the 4 levels of channel t (one float4)
    const float4 pv = reinterpret_cast<const float4*>(P)[(size_t)n * 256 + t];
    ps[t][0] = pv.x; ps[t][1] = pv.y; ps[t][2] = pv.z; ps[t][3] = pv.w;
    __syncthreads();

    if (t < 32) {
        const int l = t >> 3, oc = t & 7;   // concat channel c = l*8 + oc
        float s = 0.f;
        #pragma unroll
        for (int m = 0; m < 32; ++m) s += ps[oc * 32 + m][l];
        S[t] = s;
    }
    __syncthreads();

    if (t < 128) {
        const float scale = 0.001f / 4096.0f;   // OUT_SCALE / (H*W)
        float acc = 0.f;
        const float* wr = W + t * 32;
        #pragma unroll
        for (int c = 0; c < 32; ++c) acc += wr[c] * S[c];
        out[n * 128 + t] = fmaf(acc, scale, B[t]);
    }
}

extern "C" void kernel_launch(void* const* d_in, const int* in_sizes, int n_in,
                              void* d_out, int out_size, void* d_ws, size_t ws_size,
                              hipStream_t stream) {
    const float* z0 = (const float*)d_in[0];
    const float* z1 = (const float*)d_in[1];
    const float* z2 = (const float*)d_in[2];
    const float* z3 = (const float*)d_in[3];
    const float* x  = (const float*)d_in[4];
    const float* Wm = (const float*)d_in[5];
    const float* Bm = (const float*)d_in[6];
    float* out = (float*)d_out;
    float* P = (float*)d_ws;   // 16384*4 floats = 256 KB scratch

    hipLaunchKernelGGL(xcorr_mean_wave, dim3(4096), dim3(256), 0, stream,
                       x, z0, z1, z2, z3, P);
    hipLaunchKernelGGL(fuse_kernel, dim3(64), dim3(256), 0, stream, P, Wm, Bm, out);
}